// Round 6
// baseline (144.067 us; speedup 1.0000x reference)
//
#include <hip/hip_runtime.h>

// Gemma3n AltUp fused, R6: grid-stride software pipeline, REGULAR loads
// (L3 absorbs ~half the input re-reads — NT loads in R5 bypassed L3 and
// cost +150 MB HBM), NT stores only (output never re-read; keep L3 for input).
// Shapes: hidden_states [4, T, H], activated [T, H], w_norm [H],
//         W_router [4, H], W_pred [16, 4], W_corr [4, 4], out [4, T, H]
// T = B*S = 8192, H = 2048, fp32.

constexpr int H = 2048;
constexpr float EPS = 1e-6f;

typedef float f32x4 __attribute__((ext_vector_type(4)));

__device__ __forceinline__ void nt_store(float* p, f32x4 v) {
    __builtin_nontemporal_store(v, reinterpret_cast<f32x4*>(p));
}

__global__ __launch_bounds__(512) void altup_fused(
    const float* __restrict__ hs,       // [4, T, H]
    const float* __restrict__ act,      // [T, H]
    const float* __restrict__ w_norm,   // [H]
    const float* __restrict__ W_router, // [4, H]
    const float* __restrict__ W_pred,   // [16, 4]
    const float* __restrict__ W_corr,   // [4, 4]
    float* __restrict__ out,            // [4, T, H]
    long long T, int iters)
{
    const int tid = threadIdx.x;
    const int h = tid * 4;
    const long long plane = T * (long long)H;
    const long long strideT = gridDim.x;

    __shared__ float s_red[2][8][10];

    // ---- token-invariant operands (hoisted) ----
    const f32x4 wn = *reinterpret_cast<const f32x4*>(w_norm + h);
    f32x4 wrw[4];
#pragma unroll
    for (int i = 0; i < 4; ++i) {
        const f32x4 wr = *reinterpret_cast<const f32x4*>(W_router + i * H + h);
#pragma unroll
        for (int e = 0; e < 4; ++e) wrw[i][e] = wn[e] * wr[e];
    }

    long long t = blockIdx.x;

    // ---- prologue: first token's streaming loads (regular, L3-cacheable) ----
    f32x4 cx0 = *reinterpret_cast<const f32x4*>(hs + t * H + h);
    f32x4 cx1 = *reinterpret_cast<const f32x4*>(hs + plane + t * H + h);
    f32x4 cx2 = *reinterpret_cast<const f32x4*>(hs + 2 * plane + t * H + h);
    f32x4 cx3 = *reinterpret_cast<const f32x4*>(hs + 3 * plane + t * H + h);
    f32x4 cxc = *reinterpret_cast<const f32x4*>(act + t * H + h);

    for (int it = 0; it < iters; ++it) {
        // ---- issue NEXT token's loads before the reduce ----
        const long long tn = t + strideT;
        f32x4 nx0, nx1, nx2, nx3, nxc;
        if (it + 1 < iters) {
            nx0 = *reinterpret_cast<const f32x4*>(hs + tn * H + h);
            nx1 = *reinterpret_cast<const f32x4*>(hs + plane + tn * H + h);
            nx2 = *reinterpret_cast<const f32x4*>(hs + 2 * plane + tn * H + h);
            nx3 = *reinterpret_cast<const f32x4*>(hs + 3 * plane + tn * H + h);
            nxc = *reinterpret_cast<const f32x4*>(act + tn * H + h);
        }

        // ---- partials ----
        float p[10];
        {
            float s0 = 0.f, s5 = 0.f;
#pragma unroll
            for (int e = 0; e < 4; ++e) { s0 += cx0[e] * cx0[e]; s5 += cxc[e] * cxc[e]; }
            p[0] = s0; p[5] = s5;
#pragma unroll
            for (int i = 0; i < 4; ++i) {
                float da = 0.f, dc = 0.f;
#pragma unroll
                for (int e = 0; e < 4; ++e) {
                    da += cx0[e] * wrw[i][e];
                    dc += cxc[e] * wrw[i][e];
                }
                p[1 + i] = da; p[6 + i] = dc;
            }
        }

        // ---- wave butterfly + single-barrier cross-wave reduce (ping-pong) ----
#pragma unroll
        for (int m = 1; m < 64; m <<= 1) {
#pragma unroll
            for (int i = 0; i < 10; ++i) p[i] += __shfl_xor(p[i], m, 64);
        }
        const int buf = it & 1;
        const int wave = tid >> 6;
        if ((tid & 63) == 0) {
#pragma unroll
            for (int i = 0; i < 10; ++i) s_red[buf][wave][i] = p[i];
        }
        __syncthreads();

        float tot[10];
#pragma unroll
        for (int i = 0; i < 10; ++i) {
            float s = 0.f;
#pragma unroll
            for (int wv = 0; wv < 8; ++wv) s += s_red[buf][wv][i];
            tot[i] = s;
        }

        // ---- coefficient math (redundant per thread; scalar broadcasts) ----
        const float ris = 1.0f / (float)H;
        const float inv_a = rsqrtf(tot[0] * ris + EPS) * ris;
        const float inv_c = rsqrtf(tot[5] * ris + EPS) * ris;
        float mods[4], modsc[4];
#pragma unroll
        for (int i = 0; i < 4; ++i) {
            mods[i]  = tanhf(tot[1 + i] * inv_a);
            modsc[i] = tanhf(tot[6 + i] * inv_c);
        }
        // coefT[k][j] = sum_m mods[m] * W_pred[(j*4+k)*4 + m]  (swapaxes folded)
        float coefT[4][4];
#pragma unroll
        for (int j = 0; j < 4; ++j)
#pragma unroll
            for (int k = 0; k < 4; ++k) {
                float s = 0.f;
#pragma unroll
                for (int m = 0; m < 4; ++m) s += mods[m] * W_pred[(j * 4 + k) * 4 + m];
                coefT[k][j] = s;
            }
        float ccoef[4];
#pragma unroll
        for (int j = 0; j < 4; ++j) {
            float s = 1.0f;
#pragma unroll
            for (int m = 0; m < 4; ++m) s += modsc[m] * W_corr[j * 4 + m];
            ccoef[j] = s;
        }

        // ---- outputs (NT stores: never re-read, keep L3 for inputs) ----
        f32x4 o4[4];
#pragma unroll
        for (int e = 0; e < 4; ++e) {
            const float xk[4] = { cx0[e], cx1[e], cx2[e], cx3[e] };
            float pred[4];
#pragma unroll
            for (int j = 0; j < 4; ++j) {
                float s = xk[j]; // residual
#pragma unroll
                for (int k = 0; k < 4; ++k) s += xk[k] * coefT[k][j];
                pred[j] = s;
            }
            const float innov = cxc[e] - pred[0];
#pragma unroll
            for (int j = 0; j < 4; ++j)
                o4[j][e] = pred[j] + innov * ccoef[j];
        }
#pragma unroll
        for (int j = 0; j < 4; ++j)
            nt_store(out + j * plane + t * H + h, o4[j]);

        // ---- rotate pipeline ----
        t = tn;
        cx0 = nx0; cx1 = nx1; cx2 = nx2; cx3 = nx3; cxc = nxc;
    }
}

extern "C" void kernel_launch(void* const* d_in, const int* in_sizes, int n_in,
                              void* d_out, int out_size, void* d_ws, size_t ws_size,
                              hipStream_t stream) {
    const float* hs       = (const float*)d_in[0];
    const float* act      = (const float*)d_in[1];
    const float* w_norm   = (const float*)d_in[2];
    const float* W_router = (const float*)d_in[3];
    const float* W_pred   = (const float*)d_in[4];
    const float* W_corr   = (const float*)d_in[5];
    float* out = (float*)d_out;
    const long long T = (long long)in_sizes[0] / (4LL * H); // B*S

    int iters = 4;
    if (T % iters != 0) iters = 1;
    const unsigned grid = (unsigned)(T / iters);
    altup_fused<<<dim3(grid), dim3(512), 0, stream>>>(
        hs, act, w_norm, W_router, W_pred, W_corr, out, T, iters);
}

// Round 7
// 139.304 us; speedup vs baseline: 1.0342x; 1.0342x over previous
//
#include <hip/hip_runtime.h>

// Gemma3n AltUp fused, R7: one token per WAVE. No __syncthreads, no LDS,
// no inter-wave coupling — each 64-lane wave is an independent stream.
//   pass 1: 56 independent chunk-loads -> 10 partial sums (in registers)
//   reduce: in-wave 6-stage __shfl_xor butterfly (10 values)
//   coefs : per-lane redundant 4x4 math (scalar-broadcast weights)
//   pass 2: re-load x0/activated (L1/L2-hot) + planes 1-3, write 4 planes
// Shapes: hidden_states [4, T, H], activated [T, H], w_norm [H],
//         W_router [4, H], W_pred [16, 4], W_corr [4, 4], out [4, T, H]
// T = B*S = 8192, H = 2048, fp32. ~437 MB HBM after L3 absorption.

constexpr int H = 2048;
constexpr int NCHUNK = 8;   // H / (64 lanes * 4 floats)
constexpr float EPS = 1e-6f;

typedef float f32x4 __attribute__((ext_vector_type(4)));

__global__ __launch_bounds__(256) void altup_wave(
    const float* __restrict__ hs,       // [4, T, H]
    const float* __restrict__ act,      // [T, H]
    const float* __restrict__ w_norm,   // [H]
    const float* __restrict__ W_router, // [4, H]
    const float* __restrict__ W_pred,   // [16, 4]
    const float* __restrict__ W_corr,   // [4, 4]
    float* __restrict__ out,            // [4, T, H]
    long long T)
{
    const int lane = threadIdx.x & 63;
    const int wv   = threadIdx.x >> 6;
    const long long t = (long long)blockIdx.x * 4 + wv;
    if (t >= T) return;
    const long long row = t * (long long)H;
    const long long plane = T * (long long)H;
    const int base = lane * 4;

    // ---- pass 1: partials over 8 chunks (all loads independent) ----
    // p[0]=ssq(x0), p[1..4]=dot(x0*wn, Wr[i]), p[5]=ssq(xc), p[6..9]=dot(xc*wn, Wr[i])
    float p[10];
#pragma unroll
    for (int i = 0; i < 10; ++i) p[i] = 0.f;

#pragma unroll
    for (int c = 0; c < NCHUNK; ++c) {
        const int off = c * 256 + base;
        const f32x4 xa = *reinterpret_cast<const f32x4*>(hs + row + off);
        const f32x4 xc = *reinterpret_cast<const f32x4*>(act + row + off);
        const f32x4 wn = *reinterpret_cast<const f32x4*>(w_norm + off);
        f32x4 wr[4];
#pragma unroll
        for (int i = 0; i < 4; ++i)
            wr[i] = *reinterpret_cast<const f32x4*>(W_router + i * H + off);
#pragma unroll
        for (int e = 0; e < 4; ++e) {
            p[0] += xa[e] * xa[e];
            p[5] += xc[e] * xc[e];
            const float wa = xa[e] * wn[e];
            const float wc = xc[e] * wn[e];
#pragma unroll
            for (int i = 0; i < 4; ++i) {
                p[1 + i] += wa * wr[i][e];
                p[6 + i] += wc * wr[i][e];
            }
        }
    }

    // ---- in-wave butterfly reduce (no LDS, no barrier) ----
#pragma unroll
    for (int m = 1; m < 64; m <<= 1) {
#pragma unroll
        for (int i = 0; i < 10; ++i) p[i] += __shfl_xor(p[i], m, 64);
    }

    // ---- coefficient math (per-lane redundant; weights are s_load broadcasts) ----
    const float ris = 1.0f / (float)H;
    const float inv_a = rsqrtf(p[0] * ris + EPS) * ris;
    const float inv_c = rsqrtf(p[5] * ris + EPS) * ris;
    float mods[4], modsc[4];
#pragma unroll
    for (int i = 0; i < 4; ++i) {
        mods[i]  = tanhf(p[1 + i] * inv_a);
        modsc[i] = tanhf(p[6 + i] * inv_c);
    }
    // coefs = mods @ W_pred.T -> reshape [4][4] -> swapaxes:
    // coefT[k][j] = sum_m mods[m] * W_pred[(j*4+k)*4 + m]
    float coefT[4][4];
#pragma unroll
    for (int j = 0; j < 4; ++j)
#pragma unroll
        for (int k = 0; k < 4; ++k) {
            float s = 0.f;
#pragma unroll
            for (int m = 0; m < 4; ++m) s += mods[m] * W_pred[(j * 4 + k) * 4 + m];
            coefT[k][j] = s;
        }
    float ccoef[4];
#pragma unroll
    for (int j = 0; j < 4; ++j) {
        float s = 1.0f;
#pragma unroll
        for (int m = 0; m < 4; ++m) s += modsc[m] * W_corr[j * 4 + m];
        ccoef[j] = s;
    }

    // ---- pass 2: stream outputs (x0/xc re-loads hit L1/L2) ----
#pragma unroll
    for (int c = 0; c < NCHUNK; ++c) {
        const int off = c * 256 + base;
        const f32x4 x0 = *reinterpret_cast<const f32x4*>(hs + row + off);
        const f32x4 x1 = *reinterpret_cast<const f32x4*>(hs + plane + row + off);
        const f32x4 x2 = *reinterpret_cast<const f32x4*>(hs + 2 * plane + row + off);
        const f32x4 x3 = *reinterpret_cast<const f32x4*>(hs + 3 * plane + row + off);
        const f32x4 xc = *reinterpret_cast<const f32x4*>(act + row + off);
        f32x4 o4[4];
#pragma unroll
        for (int e = 0; e < 4; ++e) {
            const float xk[4] = { x0[e], x1[e], x2[e], x3[e] };
            float pred[4];
#pragma unroll
            for (int j = 0; j < 4; ++j) {
                float s = xk[j]; // residual
#pragma unroll
                for (int k = 0; k < 4; ++k) s += xk[k] * coefT[k][j];
                pred[j] = s;
            }
            const float innov = xc[e] - pred[0];
#pragma unroll
            for (int j = 0; j < 4; ++j)
                o4[j][e] = pred[j] + innov * ccoef[j];
        }
#pragma unroll
        for (int j = 0; j < 4; ++j)
            *reinterpret_cast<f32x4*>(out + j * plane + row + off) = o4[j];
    }
}

extern "C" void kernel_launch(void* const* d_in, const int* in_sizes, int n_in,
                              void* d_out, int out_size, void* d_ws, size_t ws_size,
                              hipStream_t stream) {
    const float* hs       = (const float*)d_in[0];
    const float* act      = (const float*)d_in[1];
    const float* w_norm   = (const float*)d_in[2];
    const float* W_router = (const float*)d_in[3];
    const float* W_pred   = (const float*)d_in[4];
    const float* W_corr   = (const float*)d_in[5];
    float* out = (float*)d_out;
    const long long T = (long long)in_sizes[0] / (4LL * H); // B*S

    const unsigned grid = (unsigned)((T + 3) / 4); // 4 tokens (waves) per block
    altup_wave<<<dim3(grid), dim3(256), 0, stream>>>(
        hs, act, w_norm, W_router, W_pred, W_corr, out, T);
}

// Round 8
// 117.463 us; speedup vs baseline: 1.2265x; 1.1859x over previous
//
#include <hip/hip_runtime.h>

// Gemma3n AltUp fused, R8: one token per 128-thread (2-wave) block, single
// pass, 4 chunks/thread. All 5 input rows live in registers; loads and
// stores are issued as 4KB-contiguous bursts per plane (DRAM page locality
// probe — every prior structure pinned at ~3.6 TB/s TCC throughput with
// 1KB-interleaved streams). Outputs recomputed per plane so no output regs
// are held across the store loop.
// Shapes: hidden_states [4, T, H], activated [T, H], w_norm [H],
//         W_router [4, H], W_pred [16, 4], W_corr [4, 4], out [4, T, H]
// T = B*S = 8192, H = 2048, fp32.

constexpr int H = 2048;
constexpr int NC = 4;          // chunks per thread: H / (128 thr * 4 floats)
constexpr float EPS = 1e-6f;

typedef float f32x4 __attribute__((ext_vector_type(4)));

__global__ __launch_bounds__(128) void altup_tok(
    const float* __restrict__ hs,       // [4, T, H]
    const float* __restrict__ act,      // [T, H]
    const float* __restrict__ w_norm,   // [H]
    const float* __restrict__ W_router, // [4, H]
    const float* __restrict__ W_pred,   // [16, 4]
    const float* __restrict__ W_corr,   // [4, 4]
    float* __restrict__ out,            // [4, T, H]
    long long T)
{
    const int tid = threadIdx.x;        // 0..127
    const long long t = blockIdx.x;
    const long long row = t * (long long)H;
    const long long plane = T * (long long)H;

    __shared__ float s_red[2][10];

    // ---- single pass: bursty per-plane loads, all rows -> registers ----
    // chunk c covers [c*512 + tid*4, +4) ; 4 consecutive 1KB wave-accesses
    // per plane = 4KB contiguous burst per stream.
    f32x4 x0[NC], xc[NC], x1[NC], x2[NC], x3[NC];
#pragma unroll
    for (int c = 0; c < NC; ++c)
        x0[c] = *reinterpret_cast<const f32x4*>(hs + row + c * 512 + tid * 4);
#pragma unroll
    for (int c = 0; c < NC; ++c)
        xc[c] = *reinterpret_cast<const f32x4*>(act + row + c * 512 + tid * 4);
#pragma unroll
    for (int c = 0; c < NC; ++c)
        x1[c] = *reinterpret_cast<const f32x4*>(hs + plane + row + c * 512 + tid * 4);
#pragma unroll
    for (int c = 0; c < NC; ++c)
        x2[c] = *reinterpret_cast<const f32x4*>(hs + 2 * plane + row + c * 512 + tid * 4);
#pragma unroll
    for (int c = 0; c < NC; ++c)
        x3[c] = *reinterpret_cast<const f32x4*>(hs + 3 * plane + row + c * 512 + tid * 4);

    // ---- partials (router/weight loads are broadcast-hot in L2/L3) ----
    float p[10];
#pragma unroll
    for (int i = 0; i < 10; ++i) p[i] = 0.f;
#pragma unroll
    for (int c = 0; c < NC; ++c) {
        const int off = c * 512 + tid * 4;
        const f32x4 wn = *reinterpret_cast<const f32x4*>(w_norm + off);
#pragma unroll
        for (int e = 0; e < 4; ++e) {
            p[0] += x0[c][e] * x0[c][e];
            p[5] += xc[c][e] * xc[c][e];
        }
#pragma unroll
        for (int i = 0; i < 4; ++i) {
            const f32x4 wr = *reinterpret_cast<const f32x4*>(W_router + i * H + off);
            float da = 0.f, dc = 0.f;
#pragma unroll
            for (int e = 0; e < 4; ++e) {
                const float wre = wn[e] * wr[e];
                da += x0[c][e] * wre;
                dc += xc[c][e] * wre;
            }
            p[1 + i] += da; p[6 + i] += dc;
        }
    }

    // ---- in-wave butterfly + single 2-wave LDS exchange ----
#pragma unroll
    for (int m = 1; m < 64; m <<= 1) {
#pragma unroll
        for (int i = 0; i < 10; ++i) p[i] += __shfl_xor(p[i], m, 64);
    }
    const int wv = tid >> 6;
    if ((tid & 63) == 0) {
#pragma unroll
        for (int i = 0; i < 10; ++i) s_red[wv][i] = p[i];
    }
    __syncthreads();
    float tot[10];
#pragma unroll
    for (int i = 0; i < 10; ++i) tot[i] = s_red[0][i] + s_red[1][i];

    // ---- coefficient math (redundant per thread) ----
    const float ris = 1.0f / (float)H;
    const float inv_a = rsqrtf(tot[0] * ris + EPS) * ris;
    const float inv_c = rsqrtf(tot[5] * ris + EPS) * ris;
    float mods[4], modsc[4];
#pragma unroll
    for (int i = 0; i < 4; ++i) {
        mods[i]  = tanhf(tot[1 + i] * inv_a);
        modsc[i] = tanhf(tot[6 + i] * inv_c);
    }
    // coefT[k][j] = sum_m mods[m] * W_pred[(j*4+k)*4 + m]  (swapaxes folded)
    float coefT[4][4];
#pragma unroll
    for (int j = 0; j < 4; ++j)
#pragma unroll
        for (int k = 0; k < 4; ++k) {
            float s = 0.f;
#pragma unroll
            for (int m = 0; m < 4; ++m) s += mods[m] * W_pred[(j * 4 + k) * 4 + m];
            coefT[k][j] = s;
        }
    float ccoef[4];
#pragma unroll
    for (int j = 0; j < 4; ++j) {
        float s = 1.0f;
#pragma unroll
        for (int m = 0; m < 4; ++m) s += modsc[m] * W_corr[j * 4 + m];
        ccoef[j] = s;
    }

    // ---- plane-major stores: 4KB contiguous burst per output plane ----
    // innovation coefficients folded: out[j] = pred[j] + (xc - pred[0])*ccoef[j]
#pragma unroll
    for (int j = 0; j < 4; ++j) {
#pragma unroll
        for (int c = 0; c < NC; ++c) {
            f32x4 o;
#pragma unroll
            for (int e = 0; e < 4; ++e) {
                const float xk[4] = { x0[c][e], x1[c][e], x2[c][e], x3[c][e] };
                // pred[j]
                float pj = xk[j];
#pragma unroll
                for (int k = 0; k < 4; ++k) pj += xk[k] * coefT[k][j];
                // pred[0]
                float p0 = xk[0];
#pragma unroll
                for (int k = 0; k < 4; ++k) p0 += xk[k] * coefT[k][0];
                o[e] = pj + (xc[c][e] - p0) * ccoef[j];
            }
            *reinterpret_cast<f32x4*>(out + j * plane + row + c * 512 + tid * 4) = o;
        }
    }
}

extern "C" void kernel_launch(void* const* d_in, const int* in_sizes, int n_in,
                              void* d_out, int out_size, void* d_ws, size_t ws_size,
                              hipStream_t stream) {
    const float* hs       = (const float*)d_in[0];
    const float* act      = (const float*)d_in[1];
    const float* w_norm   = (const float*)d_in[2];
    const float* W_router = (const float*)d_in[3];
    const float* W_pred   = (const float*)d_in[4];
    const float* W_corr   = (const float*)d_in[5];
    float* out = (float*)d_out;
    const long long T = (long long)in_sizes[0] / (4LL * H); // B*S

    altup_tok<<<dim3((unsigned)T), dim3(128), 0, stream>>>(
        hs, act, w_norm, W_router, W_pred, W_corr, out, T);
}